// Round 25
// baseline (457.213 us; speedup 1.0000x reference)
//
#include <hip/hip_runtime.h>
#include <cstdint>

typedef unsigned int u32;
typedef unsigned long long u64;
typedef unsigned short u16;

#define BATCH 4
#define A_CNT 70400
#define FEAT 27648
#define KSPLIT 12
#define KCHUNK 2304          // FEAT/KSPLIT
#define NTILE_IT 36          // KCHUNK/64

typedef __attribute__((ext_vector_type(8))) short bf16x8;
typedef __attribute__((ext_vector_type(4))) float f32x4;
typedef __attribute__((ext_vector_type(2))) u32 u32x2;
typedef __attribute__((ext_vector_type(4))) u32 u32x4;

// ---------------- workspace layout ----------------
constexpr size_t OF_KEYS = 0;                         // 4*70400*4 = 1126400
constexpr size_t OF_TBOX = OF_KEYS + 1126400;         // 114688
constexpr size_t OF_TSC  = OF_TBOX + 114688;          // 16384
constexpr size_t OF_BX1  = OF_TSC + 16384;
constexpr size_t OF_BX2  = OF_BX1 + 16384;
constexpr size_t OF_BY1  = OF_BX2 + 16384;
constexpr size_t OF_BY2  = OF_BY1 + 16384;
constexpr size_t OF_BAR  = OF_BY2 + 16384;
constexpr size_t OF_MASK = OF_BAR + 16384;            // 524288 (unused now; layout kept)
constexpr size_t OF_ROIS = OF_MASK + 524288;          // 57344
constexpr size_t OF_RSC  = OF_ROIS + 57344;           // 8192
constexpr size_t OF_BSW  = OF_RSC + 8192;             // 14155776
constexpr size_t OF_PART = OF_BSW + 14155776;         // 12*2048*256*4 = 25165824 (<= 33554432 region)
constexpr size_t WS_NEED = OF_PART + 33554432;

// ---------------- helpers ----------------
__device__ __forceinline__ u32 keyOf(float f) {
  u32 u = __float_as_uint(f);
  return (u & 0x80000000u) ? ~u : (u | 0x80000000u);
}
__device__ __forceinline__ float keyToF(u32 k) {
  u32 u = (k & 0x80000000u) ? (k ^ 0x80000000u) : ~k;
  return __uint_as_float(u);
}
__device__ __forceinline__ u16 f2bf(float f) {   // RNE f32 -> bf16
  u32 u = __float_as_uint(f);
  u32 r = 0x7FFFu + ((u >> 16) & 1u);
  return (u16)((u + r) >> 16);
}
__device__ __forceinline__ void gload_lds16(const void* g, void* l) {
  auto gp = reinterpret_cast<const __attribute__((address_space(1))) unsigned int*>(
      reinterpret_cast<uintptr_t>(g));
  auto lp = reinterpret_cast<__attribute__((address_space(3))) unsigned int*>(
      reinterpret_cast<uintptr_t>(l));
  __builtin_amdgcn_global_load_lds(gp, lp, 16, 0, 0);
}
__device__ __forceinline__ u64 shflx64(u64 v, int m) {
  u32 lo = (u32)v, hi = (u32)(v >> 32);
  lo = __shfl_xor(lo, m, 64);
  hi = __shfl_xor(hi, m, 64);
  return ((u64)hi << 32) | lo;
}
__device__ __forceinline__ u32x4 pack8(float4 a, float4 b) {
  u32x4 o;
  o.x = (u32)f2bf(a.x) | ((u32)f2bf(a.y) << 16);
  o.y = (u32)f2bf(a.z) | ((u32)f2bf(a.w) << 16);
  o.z = (u32)f2bf(b.x) | ((u32)f2bf(b.y) << 16);
  o.w = (u32)f2bf(b.z) | ((u32)f2bf(b.w) << 16);
  return o;
}

// ---------------- fatA: blocks 0-863 Bsw prep; 864-1138 wide keygen ----------------
__global__ __launch_bounds__(1024) void k_fatA(const float* __restrict__ cls,
    const float* __restrict__ Ws1, u32* __restrict__ keys, u32* __restrict__ Bsw)
{
  int bid = blockIdx.x;
  int t = threadIdx.x;
  if (bid < 864) {
    u32 w = (u32)bid * 1024u + t;        // u32x4 index (884736 total)
    u32 tile = w >> 11;
    u32 rem = w & 2047u;
    u32 n = rem >> 3;
    u32 pq = (rem & 7u) << 4;
    u32 q0 = pq ^ ((n & 7u) << 4);
    u32 col0 = tile * 64u + (q0 >> 1);
    const float* src = Ws1 + (size_t)n * FEAT + col0;
    float4 f0 = *(const float4*)src;
    float4 f1 = *(const float4*)(src + 4);
    ((u32x4*)Bsw)[w] = pack8(f0, f1);
    return;
  }
  u32 g = (u32)(bid - 864) * 1024u + t;  // 275 blocks x 1024 = 281600 exactly
  float s0 = cls[(size_t)g * 3 + 0];
  float s1 = cls[(size_t)g * 3 + 1];
  float s2 = cls[(size_t)g * 3 + 2];
  keys[g] = keyOf(fmaxf(s0, fmaxf(s1, s2)));
}

// ---------------- k_big: blocks 0-3 prop; blocks 4-195 GEMM (BM=128,BN=256, KSPLIT=12,
//                  depth-2 counted-vmcnt pipeline; 196 blocks <= 256 CUs -> single generation) ----------------
__global__ __launch_bounds__(1024) void k_big(const u32* __restrict__ keys,
    const float* __restrict__ boxes, const float* __restrict__ A,
    const u32* __restrict__ Bsw, float* __restrict__ part,
    float* __restrict__ tbox, float* __restrict__ tsc,
    float* __restrict__ bx1, float* __restrict__ bx2, float* __restrict__ by1,
    float* __restrict__ by2, float* __restrict__ bar)
{
  // 128KB: A dbuf 2x16KB [0,32768); B 3buf 3x32KB [32768,131072); prop aliases first ~17KB
  __shared__ __align__(16) char smem[131072];
  int bid = blockIdx.x;
  int t = threadIdx.x;
  if (bid < 4) {
    // ======== proposal path (verbatim R11 semantics; smem aliased) ========
    int b = bid;
    int lane = t & 63, wv = t >> 6;
    const u32* kb = keys + (size_t)b * A_CNT;
    u64* s = (u64*)smem;                       // 2048 * 8B = 16384
    u32* partials = (u32*)(smem + 16384);      // 16 * 4B
    u32* ccp = (u32*)(smem + 16448);           // 1 * 4B
    u32 h[35];
#pragma unroll
    for (int j = 0; j < 35; ++j) {
      int g0 = t + ((2 * j) << 10);
      int g1 = t + ((2 * j + 1) << 10);
      u32 a = (g0 < A_CNT) ? (kb[g0] >> 16) : 0u;
      u32 c2 = (g1 < A_CNT) ? (kb[g1] >> 16) : 0u;
      h[j] = a | (c2 << 16);
    }
    if (t == 0) ccp[0] = 0u;
    u32 lo = 0, hi = 65536;
    while (hi - lo > 1) {
      u32 mid = (lo + hi) >> 1;
      u32 c = 0;
#pragma unroll
      for (int j = 0; j < 35; ++j) {
        c += ((h[j] & 0xFFFFu) >= mid) ? 1u : 0u;
        c += ((h[j] >> 16) >= mid) ? 1u : 0u;
      }
#pragma unroll
      for (int o = 32; o > 0; o >>= 1) c += __shfl_xor(c, o, 64);
      __syncthreads();
      if (lane == 0) partials[wv] = c;
      __syncthreads();
      u32 tot = 0;
#pragma unroll
      for (int w2 = 0; w2 < 16; ++w2) tot += partials[w2];
      if (tot >= 1024u) lo = mid; else hi = mid;
    }
    u32 kth = lo;
    __syncthreads();
    u32 kc = kb[t];
#pragma unroll 1
    for (int i = 0; i < 69; ++i) {
      int g = t + (i << 10);
      u32 k = kc;
      if (i < 68) {
        int gn = t + ((i + 1) << 10);
        kc = (gn < A_CNT) ? kb[gn] : 0u;
      }
      bool pass = (g < A_CNT) && ((k >> 16) >= kth);
      u64 mm = __ballot(pass);
      if (mm) {
        int leader = __ffsll((unsigned long long)mm) - 1;
        u32 base = 0;
        if (lane == leader) base = atomicAdd(ccp, (u32)__popcll(mm));
        base = __shfl(base, leader, 64);
        if (pass) {
          u32 pos = base + (u32)__popcll(mm & ((1ull << lane) - 1ull));
          if (pos < 2048u) s[pos] = ((u64)k << 32) | (u32)(~(u32)g);
        }
      }
    }
    __syncthreads();
    u32 m = ccp[0]; if (m > 2048u) m = 2048u;
    for (int e = t; e < 2048; e += 1024) if (e >= (int)m) s[e] = 0ull;
    __syncthreads();
    {
      u64 v0 = s[2 * t], v1 = s[2 * t + 1];
#pragma unroll
      for (u32 k = 2; k <= 128; k <<= 1) {
        bool desc = ((t & (k >> 1)) == 0);
#pragma unroll
        for (u32 j = (k >> 1); j >= 2; j >>= 1) {
          u32 mmk = j >> 1;
          u64 p0 = shflx64(v0, mmk);
          u64 p1 = shflx64(v1, mmk);
          bool up = ((t & mmk) == 0);
          bool mx = (desc == up);
          v0 = mx ? (v0 > p0 ? v0 : p0) : (v0 < p0 ? v0 : p0);
          v1 = mx ? (v1 > p1 ? v1 : p1) : (v1 < p1 ? v1 : p1);
        }
        if (desc ? (v0 < v1) : (v0 > v1)) { u64 tmp = v0; v0 = v1; v1 = tmp; }
      }
      s[2 * t] = v0; s[2 * t + 1] = v1;
      __syncthreads();
      for (u32 k = 256; k <= 2048; k <<= 1) {
        for (u32 j = k >> 1; j >= 128; j >>= 1) {
          for (int e = t; e < 2048; e += 1024) {
            u32 p = (u32)e ^ j;
            if (p > (u32)e) {
              bool d2 = ((e & k) == 0);
              u64 x = s[e], y = s[p];
              if (d2 ? (x < y) : (x > y)) { s[e] = y; s[p] = x; }
            }
          }
          __syncthreads();
        }
        u64 v0 = s[2 * t], v1 = s[2 * t + 1];
        bool desc = ((t & (k >> 1)) == 0);
#pragma unroll
        for (u32 j = 64; j >= 2; j >>= 1) {
          u32 mmk = j >> 1;
          u64 p0 = shflx64(v0, mmk);
          u64 p1 = shflx64(v1, mmk);
          bool up = ((t & mmk) == 0);
          bool mx = (desc == up);
          v0 = mx ? (v0 > p0 ? v0 : p0) : (v0 < p0 ? v0 : p0);
          v1 = mx ? (v1 > p1 ? v1 : p1) : (v1 < p1 ? v1 : p1);
        }
        if (desc ? (v0 < v1) : (v0 > v1)) { u64 tmp = v0; v0 = v1; v1 = tmp; }
        s[2 * t] = v0; s[2 * t + 1] = v1;
        __syncthreads();
      }
    }
    u64 comp = s[t];
    u32 kk = (u32)(comp >> 32);
    u32 a = ~(u32)(comp & 0xFFFFFFFFull);
    int o = b * 1024 + t;
    tsc[o] = keyToF(kk);
    const float* bp = boxes + ((size_t)b * A_CNT + a) * 7;
    float x = bp[0], y = bp[1], z = bp[2], dx = bp[3], dy = bp[4], dz = bp[5], rr = bp[6];
    float* tb = tbox + (size_t)o * 7;
    tb[0] = x; tb[1] = y; tb[2] = z; tb[3] = dx; tb[4] = dy; tb[5] = dz; tb[6] = rr;
    {
#pragma clang fp contract(off)
      bx1[o] = x - 0.5f * dx; bx2[o] = x + 0.5f * dx;
      by1[o] = y - 0.5f * dy; by2[o] = y + 0.5f * dy;
      bar[o] = dx * dy;
    }
    return;
  }
  // ======== GEMM path: BM=128, BN=256; 16 waves = 4x4 grid; depth-2 counted-vmcnt pipeline ========
  int bid2 = bid - 4;                  // 0..191
  int ks = bid2 >> 4;                  // 0..11
  int mt = bid2 & 15;                  // M-tile of 128 rows
  int lane = t & 63, wvid = t >> 6;
  int row16 = lane & 15, kgrp = lane >> 4;
  int gm = wvid >> 2, gn = wvid & 3;   // wave grid 4x4

  f32x4 acc[2][4];
#pragma unroll
  for (int i = 0; i < 2; ++i)
#pragma unroll
    for (int j = 0; j < 4; ++j) acc[i][j] = (f32x4){0.f, 0.f, 0.f, 0.f};

  // A staging: thread t -> row = t>>3 (0..127), kseg = (t&7)*8 floats
  int arow = t >> 3;
  const float* ap_base = A + ((size_t)(mt * 128 + arow)) * FEAT + (size_t)ks * KCHUNK + (t & 7) * 8;
  int asw = (arow & 7) << 4;
  int awoff = arow * 128 + (((t & 7) * 16) ^ asw);
  const char* bsrc_base = (const char*)Bsw + ((size_t)(ks * NTILE_IT)) * 32768 + wvid * 2048 + lane * 16;
  int bdoff = wvid * 2048 + lane * 16;
  char* Abase = smem;
  char* Bbase = smem + 32768;

  int aoff[2][2], boff[4][2];
#pragma unroll
  for (int ksub = 0; ksub < 2; ++ksub) {
    int qq = ksub * 64 + kgrp * 16;
#pragma unroll
    for (int mf = 0; mf < 2; ++mf) {
      int row = gm * 32 + mf * 16 + row16;
      aoff[mf][ksub] = row * 128 + (qq ^ ((row & 7) << 4));
    }
#pragma unroll
    for (int nf = 0; nf < 4; ++nf) {
      int n = gn * 64 + nf * 16 + row16;
      boff[nf][ksub] = n * 128 + (qq ^ ((n & 7) << 4));
    }
  }

  // prologue: issue A(0),B(0),A(1),B(1); stage A(0); counted drain; barrier
  float4 gaold0, gaold1;
  {
    const float4* ap0 = (const float4*)ap_base;
    float4 a00 = ap0[0], a01 = ap0[1];                 // A(0)
    gload_lds16(bsrc_base, Bbase + bdoff);             // B(0) -> buf0
    gload_lds16(bsrc_base + 1024, Bbase + bdoff + 1024);
    const float4* ap1 = (const float4*)(ap_base + 64);
    gaold0 = ap1[0]; gaold1 = ap1[1];                  // A(1)
    const char* bs1 = bsrc_base + 32768;
    gload_lds16(bs1, Bbase + 32768 + bdoff);           // B(1) -> buf1
    gload_lds16(bs1 + 1024, Bbase + 32768 + bdoff + 1024);
    *(u32x4*)(Abase + awoff) = pack8(a00, a01);        // compiler waits A(0) only
    asm volatile("s_waitcnt lgkmcnt(0)" ::: "memory");
    asm volatile("s_waitcnt vmcnt(4)" ::: "memory");   // B(0) done; A(1),B(1) in flight
    __builtin_amdgcn_sched_barrier(0);
    __builtin_amdgcn_s_barrier();
  }

#pragma unroll 1
  for (int it = 0; it < NTILE_IT; ++it) {
    char* Acur = Abase + ((it & 1) << 14);
    char* Bcur = Bbase + (it % 3) * 32768;
    bool pf = (it + 2 < NTILE_IT);
    float4 gn0, gn1;
    if (pf) {
      const float4* ap = (const float4*)(ap_base + (it + 2) * 64);
      gn0 = ap[0]; gn1 = ap[1];                        // A(it+2) issued FIRST
      const char* bs = bsrc_base + (size_t)(it + 2) * 32768;
      char* Bn = Bbase + ((it + 2) % 3) * 32768;
      gload_lds16(bs, Bn + bdoff);                     // B(it+2) after A
      gload_lds16(bs + 1024, Bn + bdoff + 1024);
    }
    bf16x8 af[2][2], bf[4][2];
#pragma unroll
    for (int ksub = 0; ksub < 2; ++ksub) {
#pragma unroll
      for (int mf = 0; mf < 2; ++mf) af[mf][ksub] = *(const bf16x8*)(Acur + aoff[mf][ksub]);
#pragma unroll
      for (int nf = 0; nf < 4; ++nf) bf[nf][ksub] = *(const bf16x8*)(Bcur + boff[nf][ksub]);
    }
#pragma unroll
    for (int ksub = 0; ksub < 2; ++ksub)
#pragma unroll
      for (int mf = 0; mf < 2; ++mf)
#pragma unroll
        for (int nf = 0; nf < 4; ++nf)
          acc[mf][nf] = __builtin_amdgcn_mfma_f32_16x16x32_bf16(af[mf][ksub], bf[nf][ksub], acc[mf][nf], 0, 0, 0);
    if (it + 1 < NTILE_IT) {
      char* An = Abase + (((it + 1) & 1) << 14);
      *(u32x4*)(An + awoff) = pack8(gaold0, gaold1);   // stage A(it+1); waits its loads only
      gaold0 = gn0; gaold1 = gn1;
      asm volatile("s_waitcnt lgkmcnt(0)" ::: "memory");
      if (pf) asm volatile("s_waitcnt vmcnt(4)" ::: "memory");  // B(it+1) done; A/B(it+2) in flight
      else    asm volatile("s_waitcnt vmcnt(0)" ::: "memory");
      __builtin_amdgcn_sched_barrier(0);
      __builtin_amdgcn_s_barrier();
    }
  }
  float* pb = part + (size_t)ks * 524288;
#pragma unroll
  for (int mf = 0; mf < 2; ++mf) {
    int orow = mt * 128 + gm * 32 + mf * 16 + kgrp * 4;
#pragma unroll
    for (int nf = 0; nf < 4; ++nf) {
      int col = gn * 64 + nf * 16 + row16;
#pragma unroll
      for (int rr = 0; rr < 4; ++rr)
        pb[(size_t)(orow + rr) * 256 + col] = acc[mf][nf][rr];
    }
  }
}

// ---------------- fused mask+NMS: 4 blocks x 1024; mask in LDS (128KB, word-swizzled) ----------------
__global__ __launch_bounds__(1024) void k_nms(const float* __restrict__ bx1,
    const float* __restrict__ bx2, const float* __restrict__ by1,
    const float* __restrict__ by2, const float* __restrict__ bar,
    const float* __restrict__ tbox, const float* __restrict__ tsc,
    float* __restrict__ rois, float* __restrict__ rsc)
{
  __shared__ u32 Ml[1024 * 32];   // 128 KB; word w of row r stored at r*32 + (w ^ (r&31))
  int b = blockIdx.x, t = threadIdx.x;
  int o = b * 1024;
  // ---- phase 1: compute this batch's full suppression mask into LDS ----
  // thread t owns row r=t; identical IoU code/order to the verified k_mask
  float rx1 = bx1[o + t], rx2 = bx2[o + t], ry1 = by1[o + t], ry2 = by2[o + t], rar = bar[o + t];
#pragma unroll 1
  for (int cbk = 0; cbk < 16; ++cbk) {
    int jc0 = cbk * 64;
    u32 w0 = 0, w1 = 0;
    {
#pragma clang fp contract(off)
      for (int c = 0; c < 64; ++c) {
        int jc = jc0 + c;
        float iw = fminf(rx2, bx2[o + jc]) - fmaxf(rx1, bx1[o + jc]); iw = fmaxf(iw, 0.0f);
        float ih = fminf(ry2, by2[o + jc]) - fmaxf(ry1, by1[o + jc]); ih = fmaxf(ih, 0.0f);
        float inter = iw * ih;
        float den = fmaxf(rar + bar[o + jc] - inter, 1e-6f);
        float iou = inter / den;
        if ((iou > 0.7f) && (jc > t)) {
          if (c < 32) w0 |= 1u << c; else w1 |= 1u << (c - 32);
        }
      }
    }
    Ml[t * 32 + ((cbk * 2) ^ (t & 31))] = w0;
    Ml[t * 32 + ((cbk * 2 + 1) ^ (t & 31))] = w1;
  }
  __syncthreads();
  // ---- phase 2: serial greedy recurrence (wave 0 only), masks from LDS ----
  if (t < 64) {
    int lane = t;
    int el = lane & 31;
    u32 R = 0;
#pragma unroll 1
    for (int c = 0; c < 32; ++c) {
      u32 cur[32];
#pragma unroll
      for (int i = 0; i < 32; ++i) {
        int row = c * 32 + i;
        cur[i] = Ml[row * 32 + (el ^ (row & 31))];
      }
      u32 w = R;
#pragma unroll
      for (int i = 0; i < 32; ++i) w |= ((w >> i) & 1u) ? 0u : cur[i];
      u32 wfin = __shfl(w, c, 64);
      u32 m0 = 0, m1 = 0, m2 = 0, m3 = 0;
#pragma unroll
      for (int i = 0; i < 32; i += 4) {
        m0 |= ((wfin >> (i + 0)) & 1u) ? 0u : cur[i + 0];
        m1 |= ((wfin >> (i + 1)) & 1u) ? 0u : cur[i + 1];
        m2 |= ((wfin >> (i + 2)) & 1u) ? 0u : cur[i + 2];
        m3 |= ((wfin >> (i + 3)) & 1u) ? 0u : cur[i + 3];
      }
      R |= (m0 | m1) | (m2 | m3);
    }
    u32 keepw = (lane < 32) ? ~R : 0u;
    int c = __popc(keepw);
    int pre = c;
    for (int d = 1; d < 64; d <<= 1) {
      int v = __shfl_up(pre, d, 64);
      if (lane >= d) pre += v;
    }
    int total = __shfl(pre, 31, 64);
    int base = pre - c;
    if (lane < 32) {
      u32 w = keepw;
      int rank = base;
      while (w) {
        int bit = __ffs(w) - 1;
        w &= w - 1;
        if (rank < 512) {
          int r = lane * 32 + bit;
          const float* tb = tbox + ((size_t)b * 1024 + r) * 7;
          float* rp = rois + ((size_t)b * 512 + rank) * 7;
          rp[0] = tb[0]; rp[1] = tb[1]; rp[2] = tb[2]; rp[3] = tb[3];
          rp[4] = tb[4]; rp[5] = tb[5]; rp[6] = tb[6];
          rsc[b * 512 + rank] = tsc[b * 1024 + r];
        }
        rank++;
      }
    }
    for (int z = total + lane; z < 512; z += 64) {
      float* rp = rois + ((size_t)b * 512 + z) * 7;
      rp[0] = rp[1] = rp[2] = rp[3] = rp[4] = rp[5] = rp[6] = 0.0f;
      rsc[b * 512 + z] = 0.0f;
    }
  }
}

// ---------------- one 256x256 layer (4 rows per thread-half) + BN + ReLU ----------------
__device__ __forceinline__ void layer4(const float (*IN)[256], const float* __restrict__ W,
    const float* __restrict__ g, const float* __restrict__ bb, float (*OUT)[256], int t, int h)
{
  float acc[4] = {0, 0, 0, 0};
  const float* Wrow = W + (size_t)t * 256;
  for (int k = 0; k < 256; k += 4) {
    float4 w4 = *(const float4*)&Wrow[k];
#pragma unroll
    for (int r = 0; r < 4; ++r) {
      float4 xv = *(const float4*)&IN[h * 4 + r][k];
      acc[r] = fmaf(xv.x, w4.x, acc[r]);
      acc[r] = fmaf(xv.y, w4.y, acc[r]);
      acc[r] = fmaf(xv.z, w4.z, acc[r]);
      acc[r] = fmaf(xv.w, w4.w, acc[r]);
    }
  }
  float sc = g[t] / sqrtf(1.0f + 1e-5f);
  float bv = bb[t];
#pragma unroll
  for (int r = 0; r < 4; ++r)
    OUT[h * 4 + r][t] = fmaxf(fmaf(acc[r], sc, bv), 0.0f);
}

// ---------------- fused head chain (512 threads) ----------------
__global__ __launch_bounds__(512) void k_chain(const float* __restrict__ part,
    const float* __restrict__ Ws2, const float* __restrict__ Wc1, const float* __restrict__ Wc2,
    const float* __restrict__ Wr1, const float* __restrict__ Wr2,
    const float* __restrict__ g1, const float* __restrict__ b1,
    const float* __restrict__ g2, const float* __restrict__ b2,
    const float* __restrict__ gc1, const float* __restrict__ bc1,
    const float* __restrict__ gc2, const float* __restrict__ bc2,
    const float* __restrict__ gr1, const float* __restrict__ br1,
    const float* __restrict__ gr2, const float* __restrict__ br2,
    const float* __restrict__ Wc3, const float* __restrict__ bc3,
    const float* __restrict__ Wr3, const float* __restrict__ br3,
    const float* __restrict__ rois, const float* __restrict__ rsc,
    float* __restrict__ out)
{
  int bid = blockIdx.x, tid = threadIdx.x;
  int t = tid & 255, h = tid >> 8;
  __shared__ __align__(16) float bufX[8][256];
  __shared__ __align__(16) float bufY[8][256];
  __shared__ __align__(16) float bufC[8][256];
  __shared__ __align__(16) float bufR[8][256];
  __shared__ float hd[64];
  {
    float sc = g1[t] / sqrtf(1.0f + 1e-5f);
    float bv = b1[t];
#pragma unroll
    for (int r = 0; r < 4; ++r) {
      int row = h * 4 + r;
      float s = 0.f;
#pragma unroll
      for (int ks = 0; ks < KSPLIT; ++ks)
        s += part[(size_t)ks * 524288 + (size_t)(bid * 8 + row) * 256 + t];
      bufX[row][t] = fmaxf(fmaf(s, sc, bv), 0.0f);
    }
  }
  __syncthreads();
  layer4(bufX, Ws2, g2, b2, bufY, t, h);
  __syncthreads();
  layer4(bufY, Wc1, gc1, bc1, bufC, t, h);
  layer4(bufY, Wr1, gr1, br1, bufR, t, h);
  __syncthreads();
  layer4(bufC, Wc2, gc2, bc2, bufX, t, h);
  layer4(bufR, Wr2, gr2, br2, bufY, t, h);
  __syncthreads();
  int wv = tid >> 6, ln = tid & 63;
  for (int task = wv; task < 64; task += 8) {
    float p;
    if (task < 8) {
      float4 yv = *(const float4*)&bufX[task][ln * 4];
      float4 w4 = ((const float4*)Wc3)[ln];
      p = yv.x * w4.x + yv.y * w4.y + yv.z * w4.z + yv.w * w4.w;
    } else {
      int i = task - 8, row = i / 7, j = i % 7;
      float4 yv = *(const float4*)&bufY[row][ln * 4];
      float4 w4 = ((const float4*)(Wr3 + j * 256))[ln];
      p = yv.x * w4.x + yv.y * w4.y + yv.z * w4.z + yv.w * w4.w;
    }
#pragma unroll
    for (int off = 32; off > 0; off >>= 1) p += __shfl_xor(p, off, 64);
    if (ln == 0) hd[task] = p;
  }
  __syncthreads();
  if (tid < 8) {
    int m = bid * 8 + tid;
    float clsv = hd[tid] + bc3[0];
    float rg[7];
#pragma unroll
    for (int j = 0; j < 7; ++j) rg[j] = hd[8 + tid * 7 + j] + br3[j];
    const float* R = rois + (size_t)m * 7;
    float rx = R[0], ry = R[1], rz = R[2], dxa = R[3], dya = R[4], dza = R[5], ra = R[6];
    float diag = sqrtf(dxa * dxa + dya * dya);
    float x = rg[0] * diag, y = rg[1] * diag, z = rg[2] * dza;
    float ex = expf(rg[3]) * dxa, ey = expf(rg[4]) * dya, ez = expf(rg[5]) * dza;
    float hr = rg[6] + ra;
    float cc = cosf(ra), sn = sinf(ra);
    float xr = x * cc - y * sn, yr = x * sn + y * cc;
    float* O = out + (size_t)m * 9;
    O[0] = clsv; O[1] = xr + rx; O[2] = yr + ry; O[3] = z + rz;
    O[4] = ex; O[5] = ey; O[6] = ez; O[7] = hr; O[8] = rsc[m];
  }
}

// ---------------- launch ----------------
extern "C" void kernel_launch(void* const* d_in, const int* in_sizes, int n_in,
                              void* d_out, int out_size, void* d_ws, size_t ws_size,
                              hipStream_t stream)
{
  const float* rpn_box = (const float*)d_in[0];
  const float* rpn_cls = (const float*)d_in[1];
  const float* pooled  = (const float*)d_in[2];
  const float* Ws1 = (const float*)d_in[3];
  const float* g1  = (const float*)d_in[4];
  const float* b1  = (const float*)d_in[5];
  const float* Ws2 = (const float*)d_in[6];
  const float* g2  = (const float*)d_in[7];
  const float* b2  = (const float*)d_in[8];
  const float* Wc1 = (const float*)d_in[9];
  const float* gc1 = (const float*)d_in[10];
  const float* bc1 = (const float*)d_in[11];
  const float* Wc2 = (const float*)d_in[12];
  const float* gc2 = (const float*)d_in[13];
  const float* bc2 = (const float*)d_in[14];
  const float* Wc3 = (const float*)d_in[15];
  const float* bc3 = (const float*)d_in[16];
  const float* Wr1 = (const float*)d_in[17];
  const float* gr1 = (const float*)d_in[18];
  const float* br1 = (const float*)d_in[19];
  const float* Wr2 = (const float*)d_in[20];
  const float* gr2 = (const float*)d_in[21];
  const float* br2 = (const float*)d_in[22];
  const float* Wr3 = (const float*)d_in[23];
  const float* br3 = (const float*)d_in[24];

  if (ws_size < WS_NEED) return;

  char* ws = (char*)d_ws;
  u32* keys = (u32*)(ws + OF_KEYS);
  float* tbox = (float*)(ws + OF_TBOX);
  float* tsc  = (float*)(ws + OF_TSC);
  float* bx1 = (float*)(ws + OF_BX1);
  float* bx2 = (float*)(ws + OF_BX2);
  float* by1 = (float*)(ws + OF_BY1);
  float* by2 = (float*)(ws + OF_BY2);
  float* bar = (float*)(ws + OF_BAR);
  float* roisb = (float*)(ws + OF_ROIS);
  float* rscb  = (float*)(ws + OF_RSC);
  u32* Bsw = (u32*)(ws + OF_BSW);
  float* part = (float*)(ws + OF_PART);

  k_fatA<<<1139, 1024, 0, stream>>>(rpn_cls, Ws1, keys, Bsw);
  k_big<<<196, 1024, 0, stream>>>(keys, rpn_box, pooled, Bsw, part,
                                  tbox, tsc, bx1, bx2, by1, by2, bar);
  k_nms<<<4, 1024, 0, stream>>>(bx1, bx2, by1, by2, bar, tbox, tsc, roisb, rscb);
  k_chain<<<256, 512, 0, stream>>>(part, Ws2, Wc1, Wc2, Wr1, Wr2,
                                   g1, b1, g2, b2, gc1, bc1, gc2, bc2,
                                   gr1, br1, gr2, br2, Wc3, bc3, Wr3, br3,
                                   roisb, rscb, (float*)d_out);
}

// Round 26
// 216.251 us; speedup vs baseline: 2.1143x; 2.1143x over previous
//
#include <hip/hip_runtime.h>
#include <cstdint>

typedef unsigned int u32;
typedef unsigned long long u64;
typedef unsigned short u16;

#define BATCH 4
#define A_CNT 70400
#define FEAT 27648
#define KSPLIT 12
#define KCHUNK 2304          // FEAT/KSPLIT
#define NTILE_IT 36          // KCHUNK/64

typedef __attribute__((ext_vector_type(8))) short bf16x8;
typedef __attribute__((ext_vector_type(4))) float f32x4;
typedef __attribute__((ext_vector_type(2))) u32 u32x2;
typedef __attribute__((ext_vector_type(4))) u32 u32x4;

// ---------------- workspace layout ----------------
constexpr size_t OF_KEYS = 0;                         // 4*70400*4 = 1126400
constexpr size_t OF_TBOX = OF_KEYS + 1126400;         // 114688
constexpr size_t OF_TSC  = OF_TBOX + 114688;          // 16384
constexpr size_t OF_BX1  = OF_TSC + 16384;
constexpr size_t OF_BX2  = OF_BX1 + 16384;
constexpr size_t OF_BY1  = OF_BX2 + 16384;
constexpr size_t OF_BY2  = OF_BY1 + 16384;
constexpr size_t OF_BAR  = OF_BY2 + 16384;
constexpr size_t OF_MASK = OF_BAR + 16384;            // 524288
constexpr size_t OF_ROIS = OF_MASK + 524288;          // 57344
constexpr size_t OF_RSC  = OF_ROIS + 57344;           // 8192
constexpr size_t OF_BSW  = OF_RSC + 8192;             // 14155776
constexpr size_t OF_PART = OF_BSW + 14155776;         // 12*2048*256*4 = 25165824 (<= 33554432 region)
constexpr size_t WS_NEED = OF_PART + 33554432;

// ---------------- helpers ----------------
__device__ __forceinline__ u32 keyOf(float f) {
  u32 u = __float_as_uint(f);
  return (u & 0x80000000u) ? ~u : (u | 0x80000000u);
}
__device__ __forceinline__ float keyToF(u32 k) {
  u32 u = (k & 0x80000000u) ? (k ^ 0x80000000u) : ~k;
  return __uint_as_float(u);
}
__device__ __forceinline__ u16 f2bf(float f) {   // RNE f32 -> bf16
  u32 u = __float_as_uint(f);
  u32 r = 0x7FFFu + ((u >> 16) & 1u);
  return (u16)((u + r) >> 16);
}
__device__ __forceinline__ void gload_lds16(const void* g, void* l) {
  auto gp = reinterpret_cast<const __attribute__((address_space(1))) unsigned int*>(
      reinterpret_cast<uintptr_t>(g));
  auto lp = reinterpret_cast<__attribute__((address_space(3))) unsigned int*>(
      reinterpret_cast<uintptr_t>(l));
  __builtin_amdgcn_global_load_lds(gp, lp, 16, 0, 0);
}
__device__ __forceinline__ u64 shflx64(u64 v, int m) {
  u32 lo = (u32)v, hi = (u32)(v >> 32);
  lo = __shfl_xor(lo, m, 64);
  hi = __shfl_xor(hi, m, 64);
  return ((u64)hi << 32) | lo;
}
__device__ __forceinline__ u32x4 pack8(float4 a, float4 b) {
  u32x4 o;
  o.x = (u32)f2bf(a.x) | ((u32)f2bf(a.y) << 16);
  o.y = (u32)f2bf(a.z) | ((u32)f2bf(a.w) << 16);
  o.z = (u32)f2bf(b.x) | ((u32)f2bf(b.y) << 16);
  o.w = (u32)f2bf(b.z) | ((u32)f2bf(b.w) << 16);
  return o;
}

// ---------------- fatA: blocks 0-863 Bsw prep; 864-1138 wide keygen ----------------
__global__ __launch_bounds__(1024) void k_fatA(const float* __restrict__ cls,
    const float* __restrict__ Ws1, u32* __restrict__ keys, u32* __restrict__ Bsw)
{
  int bid = blockIdx.x;
  int t = threadIdx.x;
  if (bid < 864) {
    u32 w = (u32)bid * 1024u + t;        // u32x4 index (884736 total)
    u32 tile = w >> 11;
    u32 rem = w & 2047u;
    u32 n = rem >> 3;
    u32 pq = (rem & 7u) << 4;
    u32 q0 = pq ^ ((n & 7u) << 4);
    u32 col0 = tile * 64u + (q0 >> 1);
    const float* src = Ws1 + (size_t)n * FEAT + col0;
    float4 f0 = *(const float4*)src;
    float4 f1 = *(const float4*)(src + 4);
    ((u32x4*)Bsw)[w] = pack8(f0, f1);
    return;
  }
  u32 g = (u32)(bid - 864) * 1024u + t;  // 275 blocks x 1024 = 281600 exactly
  float s0 = cls[(size_t)g * 3 + 0];
  float s1 = cls[(size_t)g * 3 + 1];
  float s2 = cls[(size_t)g * 3 + 2];
  keys[g] = keyOf(fmaxf(s0, fmaxf(s1, s2)));
}

// ---------------- k_big: blocks 0-3 prop; blocks 4-195 GEMM (BM=128,BN=256, KSPLIT=12,
//                  depth-2 counted-vmcnt pipeline; 196 blocks <= 256 CUs -> single generation) ----------------
__global__ __launch_bounds__(1024) void k_big(const u32* __restrict__ keys,
    const float* __restrict__ boxes, const float* __restrict__ A,
    const u32* __restrict__ Bsw, float* __restrict__ part,
    float* __restrict__ tbox, float* __restrict__ tsc,
    float* __restrict__ bx1, float* __restrict__ bx2, float* __restrict__ by1,
    float* __restrict__ by2, float* __restrict__ bar)
{
  // 128KB: A dbuf 2x16KB [0,32768); B 3buf 3x32KB [32768,131072); prop aliases first ~17KB
  __shared__ __align__(16) char smem[131072];
  int bid = blockIdx.x;
  int t = threadIdx.x;
  if (bid < 4) {
    // ======== proposal path (verbatim R11 semantics; smem aliased) ========
    int b = bid;
    int lane = t & 63, wv = t >> 6;
    const u32* kb = keys + (size_t)b * A_CNT;
    u64* s = (u64*)smem;                       // 2048 * 8B = 16384
    u32* partials = (u32*)(smem + 16384);      // 16 * 4B
    u32* ccp = (u32*)(smem + 16448);           // 1 * 4B
    u32 h[35];
#pragma unroll
    for (int j = 0; j < 35; ++j) {
      int g0 = t + ((2 * j) << 10);
      int g1 = t + ((2 * j + 1) << 10);
      u32 a = (g0 < A_CNT) ? (kb[g0] >> 16) : 0u;
      u32 c2 = (g1 < A_CNT) ? (kb[g1] >> 16) : 0u;
      h[j] = a | (c2 << 16);
    }
    if (t == 0) ccp[0] = 0u;
    u32 lo = 0, hi = 65536;
    while (hi - lo > 1) {
      u32 mid = (lo + hi) >> 1;
      u32 c = 0;
#pragma unroll
      for (int j = 0; j < 35; ++j) {
        c += ((h[j] & 0xFFFFu) >= mid) ? 1u : 0u;
        c += ((h[j] >> 16) >= mid) ? 1u : 0u;
      }
#pragma unroll
      for (int o = 32; o > 0; o >>= 1) c += __shfl_xor(c, o, 64);
      __syncthreads();
      if (lane == 0) partials[wv] = c;
      __syncthreads();
      u32 tot = 0;
#pragma unroll
      for (int w2 = 0; w2 < 16; ++w2) tot += partials[w2];
      if (tot >= 1024u) lo = mid; else hi = mid;
    }
    u32 kth = lo;
    __syncthreads();
    u32 kc = kb[t];
#pragma unroll 1
    for (int i = 0; i < 69; ++i) {
      int g = t + (i << 10);
      u32 k = kc;
      if (i < 68) {
        int gn = t + ((i + 1) << 10);
        kc = (gn < A_CNT) ? kb[gn] : 0u;
      }
      bool pass = (g < A_CNT) && ((k >> 16) >= kth);
      u64 mm = __ballot(pass);
      if (mm) {
        int leader = __ffsll((unsigned long long)mm) - 1;
        u32 base = 0;
        if (lane == leader) base = atomicAdd(ccp, (u32)__popcll(mm));
        base = __shfl(base, leader, 64);
        if (pass) {
          u32 pos = base + (u32)__popcll(mm & ((1ull << lane) - 1ull));
          if (pos < 2048u) s[pos] = ((u64)k << 32) | (u32)(~(u32)g);
        }
      }
    }
    __syncthreads();
    u32 m = ccp[0]; if (m > 2048u) m = 2048u;
    for (int e = t; e < 2048; e += 1024) if (e >= (int)m) s[e] = 0ull;
    __syncthreads();
    {
      u64 v0 = s[2 * t], v1 = s[2 * t + 1];
#pragma unroll
      for (u32 k = 2; k <= 128; k <<= 1) {
        bool desc = ((t & (k >> 1)) == 0);
#pragma unroll
        for (u32 j = (k >> 1); j >= 2; j >>= 1) {
          u32 mmk = j >> 1;
          u64 p0 = shflx64(v0, mmk);
          u64 p1 = shflx64(v1, mmk);
          bool up = ((t & mmk) == 0);
          bool mx = (desc == up);
          v0 = mx ? (v0 > p0 ? v0 : p0) : (v0 < p0 ? v0 : p0);
          v1 = mx ? (v1 > p1 ? v1 : p1) : (v1 < p1 ? v1 : p1);
        }
        if (desc ? (v0 < v1) : (v0 > v1)) { u64 tmp = v0; v0 = v1; v1 = tmp; }
      }
      s[2 * t] = v0; s[2 * t + 1] = v1;
      __syncthreads();
      for (u32 k = 256; k <= 2048; k <<= 1) {
        for (u32 j = k >> 1; j >= 128; j >>= 1) {
          for (int e = t; e < 2048; e += 1024) {
            u32 p = (u32)e ^ j;
            if (p > (u32)e) {
              bool d2 = ((e & k) == 0);
              u64 x = s[e], y = s[p];
              if (d2 ? (x < y) : (x > y)) { s[e] = y; s[p] = x; }
            }
          }
          __syncthreads();
        }
        u64 v0 = s[2 * t], v1 = s[2 * t + 1];
        bool desc = ((t & (k >> 1)) == 0);
#pragma unroll
        for (u32 j = 64; j >= 2; j >>= 1) {
          u32 mmk = j >> 1;
          u64 p0 = shflx64(v0, mmk);
          u64 p1 = shflx64(v1, mmk);
          bool up = ((t & mmk) == 0);
          bool mx = (desc == up);
          v0 = mx ? (v0 > p0 ? v0 : p0) : (v0 < p0 ? v0 : p0);
          v1 = mx ? (v1 > p1 ? v1 : p1) : (v1 < p1 ? v1 : p1);
        }
        if (desc ? (v0 < v1) : (v0 > v1)) { u64 tmp = v0; v0 = v1; v1 = tmp; }
        s[2 * t] = v0; s[2 * t + 1] = v1;
        __syncthreads();
      }
    }
    u64 comp = s[t];
    u32 kk = (u32)(comp >> 32);
    u32 a = ~(u32)(comp & 0xFFFFFFFFull);
    int o = b * 1024 + t;
    tsc[o] = keyToF(kk);
    const float* bp = boxes + ((size_t)b * A_CNT + a) * 7;
    float x = bp[0], y = bp[1], z = bp[2], dx = bp[3], dy = bp[4], dz = bp[5], rr = bp[6];
    float* tb = tbox + (size_t)o * 7;
    tb[0] = x; tb[1] = y; tb[2] = z; tb[3] = dx; tb[4] = dy; tb[5] = dz; tb[6] = rr;
    {
#pragma clang fp contract(off)
      bx1[o] = x - 0.5f * dx; bx2[o] = x + 0.5f * dx;
      by1[o] = y - 0.5f * dy; by2[o] = y + 0.5f * dy;
      bar[o] = dx * dy;
    }
    return;
  }
  // ======== GEMM path: BM=128, BN=256; 16 waves = 4x4 grid; depth-2 counted-vmcnt pipeline ========
  int bid2 = bid - 4;                  // 0..191
  int ks = bid2 >> 4;                  // 0..11
  int mt = bid2 & 15;                  // M-tile of 128 rows
  int lane = t & 63, wvid = t >> 6;
  int row16 = lane & 15, kgrp = lane >> 4;
  int gm = wvid >> 2, gn = wvid & 3;   // wave grid 4x4

  f32x4 acc[2][4];
#pragma unroll
  for (int i = 0; i < 2; ++i)
#pragma unroll
    for (int j = 0; j < 4; ++j) acc[i][j] = (f32x4){0.f, 0.f, 0.f, 0.f};

  // A staging: thread t -> row = t>>3 (0..127), kseg = (t&7)*8 floats
  int arow = t >> 3;
  const float* ap_base = A + ((size_t)(mt * 128 + arow)) * FEAT + (size_t)ks * KCHUNK + (t & 7) * 8;
  int asw = (arow & 7) << 4;
  int awoff = arow * 128 + (((t & 7) * 16) ^ asw);
  const char* bsrc_base = (const char*)Bsw + ((size_t)(ks * NTILE_IT)) * 32768 + wvid * 2048 + lane * 16;
  int bdoff = wvid * 2048 + lane * 16;
  char* Abase = smem;
  char* Bbase = smem + 32768;

  int aoff[2][2], boff[4][2];
#pragma unroll
  for (int ksub = 0; ksub < 2; ++ksub) {
    int qq = ksub * 64 + kgrp * 16;
#pragma unroll
    for (int mf = 0; mf < 2; ++mf) {
      int row = gm * 32 + mf * 16 + row16;
      aoff[mf][ksub] = row * 128 + (qq ^ ((row & 7) << 4));
    }
#pragma unroll
    for (int nf = 0; nf < 4; ++nf) {
      int n = gn * 64 + nf * 16 + row16;
      boff[nf][ksub] = n * 128 + (qq ^ ((n & 7) << 4));
    }
  }

  // prologue: issue A(0),B(0),A(1),B(1); stage A(0); counted drain; barrier
  float4 gaold0, gaold1;
  {
    const float4* ap0 = (const float4*)ap_base;
    float4 a00 = ap0[0], a01 = ap0[1];                 // A(0)
    gload_lds16(bsrc_base, Bbase + bdoff);             // B(0) -> buf0
    gload_lds16(bsrc_base + 1024, Bbase + bdoff + 1024);
    const float4* ap1 = (const float4*)(ap_base + 64);
    gaold0 = ap1[0]; gaold1 = ap1[1];                  // A(1)
    const char* bs1 = bsrc_base + 32768;
    gload_lds16(bs1, Bbase + 32768 + bdoff);           // B(1) -> buf1
    gload_lds16(bs1 + 1024, Bbase + 32768 + bdoff + 1024);
    *(u32x4*)(Abase + awoff) = pack8(a00, a01);        // compiler waits A(0) only
    asm volatile("s_waitcnt lgkmcnt(0)" ::: "memory");
    asm volatile("s_waitcnt vmcnt(4)" ::: "memory");   // B(0) done; A(1),B(1) in flight
    __builtin_amdgcn_sched_barrier(0);
    __builtin_amdgcn_s_barrier();
  }

#pragma unroll 1
  for (int it = 0; it < NTILE_IT; ++it) {
    char* Acur = Abase + ((it & 1) << 14);
    char* Bcur = Bbase + (it % 3) * 32768;
    bool pf = (it + 2 < NTILE_IT);
    float4 gn0, gn1;
    if (pf) {
      const float4* ap = (const float4*)(ap_base + (it + 2) * 64);
      gn0 = ap[0]; gn1 = ap[1];                        // A(it+2) issued FIRST
      const char* bs = bsrc_base + (size_t)(it + 2) * 32768;
      char* Bn = Bbase + ((it + 2) % 3) * 32768;
      gload_lds16(bs, Bn + bdoff);                     // B(it+2) after A
      gload_lds16(bs + 1024, Bn + bdoff + 1024);
    }
    bf16x8 af[2][2], bf[4][2];
#pragma unroll
    for (int ksub = 0; ksub < 2; ++ksub) {
#pragma unroll
      for (int mf = 0; mf < 2; ++mf) af[mf][ksub] = *(const bf16x8*)(Acur + aoff[mf][ksub]);
#pragma unroll
      for (int nf = 0; nf < 4; ++nf) bf[nf][ksub] = *(const bf16x8*)(Bcur + boff[nf][ksub]);
    }
#pragma unroll
    for (int ksub = 0; ksub < 2; ++ksub)
#pragma unroll
      for (int mf = 0; mf < 2; ++mf)
#pragma unroll
        for (int nf = 0; nf < 4; ++nf)
          acc[mf][nf] = __builtin_amdgcn_mfma_f32_16x16x32_bf16(af[mf][ksub], bf[nf][ksub], acc[mf][nf], 0, 0, 0);
    if (it + 1 < NTILE_IT) {
      char* An = Abase + (((it + 1) & 1) << 14);
      *(u32x4*)(An + awoff) = pack8(gaold0, gaold1);   // stage A(it+1); waits its loads only
      gaold0 = gn0; gaold1 = gn1;
      asm volatile("s_waitcnt lgkmcnt(0)" ::: "memory");
      if (pf) asm volatile("s_waitcnt vmcnt(4)" ::: "memory");  // B(it+1) done; A/B(it+2) in flight
      else    asm volatile("s_waitcnt vmcnt(0)" ::: "memory");
      __builtin_amdgcn_sched_barrier(0);
      __builtin_amdgcn_s_barrier();
    }
  }
  float* pb = part + (size_t)ks * 524288;
#pragma unroll
  for (int mf = 0; mf < 2; ++mf) {
    int orow = mt * 128 + gm * 32 + mf * 16 + kgrp * 4;
#pragma unroll
    for (int nf = 0; nf < 4; ++nf) {
      int col = gn * 64 + nf * 16 + row16;
#pragma unroll
      for (int rr = 0; rr < 4; ++rr)
        pb[(size_t)(orow + rr) * 256 + col] = acc[mf][nf][rr];
    }
  }
}

// ---------------- k_mask: 64 blocks x 1024 (16 units of 64 lanes each) ----------------
__global__ __launch_bounds__(1024) void k_mask(const float* __restrict__ bx1,
    const float* __restrict__ bx2, const float* __restrict__ by1,
    const float* __restrict__ by2, const float* __restrict__ bar,
    u32* __restrict__ mask)
{
  __shared__ float csm[16][5][64];
  int tt = threadIdx.x;
  int ug = tt >> 6, ln = tt & 63;
  int unit = blockIdx.x * 16 + ug;          // 0..1023
  int b = unit >> 8, cbk = (unit >> 4) & 15, rb = unit & 15;
  int o = b * 1024, jc0 = cbk * 64;
  int r = rb * 64 + ln;
  csm[ug][0][ln] = bx1[o + jc0 + ln];
  csm[ug][1][ln] = bx2[o + jc0 + ln];
  csm[ug][2][ln] = by1[o + jc0 + ln];
  csm[ug][3][ln] = by2[o + jc0 + ln];
  csm[ug][4][ln] = bar[o + jc0 + ln];
  __syncthreads();
  float rx1 = bx1[o + r], rx2 = bx2[o + r], ry1 = by1[o + r], ry2 = by2[o + r], rar = bar[o + r];
  u32 w0 = 0, w1 = 0;
  {
#pragma clang fp contract(off)
    for (int c = 0; c < 64; ++c) {
      int jc = jc0 + c;
      float iw = fminf(rx2, csm[ug][1][c]) - fmaxf(rx1, csm[ug][0][c]); iw = fmaxf(iw, 0.0f);
      float ih = fminf(ry2, csm[ug][3][c]) - fmaxf(ry1, csm[ug][2][c]); ih = fmaxf(ih, 0.0f);
      float inter = iw * ih;
      float den = fmaxf(rar + csm[ug][4][c] - inter, 1e-6f);
      float iou = inter / den;
      if ((iou > 0.7f) && (jc > r)) {
        if (c < 32) w0 |= 1u << c; else w1 |= 1u << (c - 32);
      }
    }
  }
  mask[((size_t)(o + r)) * 32 + cbk * 2 + 0] = w0;
  mask[((size_t)(o + r)) * 32 + cbk * 2 + 1] = w1;
}

// ---------------- chunked greedy NMS: tree-applied ORs (exact reassociation) ----------------
#define CHUNK_STEP(CUR, NXT, C) do {                                            \
    if ((C) + 1 < 32) {                                                         \
      int nb = ((C) + 1) * 1024 + el;                                           \
      _Pragma("unroll")                                                         \
      for (int i = 0; i < 32; ++i) NXT[i] = M[(size_t)(nb + i * 32)];           \
    }                                                                           \
    u32 w = R;                                                                  \
    _Pragma("unroll")                                                           \
    for (int i = 0; i < 32; ++i) w |= ((w >> i) & 1u) ? 0u : CUR[i];            \
    u32 wfin = __shfl(w, (C), 64);                                              \
    u32 m0 = 0, m1 = 0, m2 = 0, m3 = 0;                                         \
    _Pragma("unroll")                                                           \
    for (int i = 0; i < 32; i += 4) {                                           \
      m0 |= ((wfin >> (i + 0)) & 1u) ? 0u : CUR[i + 0];                         \
      m1 |= ((wfin >> (i + 1)) & 1u) ? 0u : CUR[i + 1];                         \
      m2 |= ((wfin >> (i + 2)) & 1u) ? 0u : CUR[i + 2];                         \
      m3 |= ((wfin >> (i + 3)) & 1u) ? 0u : CUR[i + 3];                         \
    }                                                                           \
    R |= (m0 | m1) | (m2 | m3);                                                 \
  } while (0)

__global__ __launch_bounds__(64) void k_nms(const u32* __restrict__ mask,
    const float* __restrict__ tbox, const float* __restrict__ tsc,
    float* __restrict__ rois, float* __restrict__ rsc)
{
  int b = blockIdx.x;
  int lane = threadIdx.x;
  int el = lane & 31;
  const u32* M = mask + (size_t)b * 1024 * 32;
  u32 R = 0;
  u32 bufA[32], bufB[32];
#pragma unroll
  for (int i = 0; i < 32; ++i) bufA[i] = M[(size_t)(i * 32 + el)];
#pragma unroll 1
  for (int c = 0; c < 32; c += 2) {
    CHUNK_STEP(bufA, bufB, c);
    CHUNK_STEP(bufB, bufA, c + 1);
  }
  u32 keepw = (lane < 32) ? ~R : 0u;
  int c = __popc(keepw);
  int pre = c;
  for (int d = 1; d < 64; d <<= 1) {
    int v = __shfl_up(pre, d, 64);
    if (lane >= d) pre += v;
  }
  int total = __shfl(pre, 31, 64);
  int base = pre - c;
  if (lane < 32) {
    u32 w = keepw;
    int rank = base;
    while (w) {
      int bit = __ffs(w) - 1;
      w &= w - 1;
      if (rank < 512) {
        int r = lane * 32 + bit;
        const float* tb = tbox + ((size_t)b * 1024 + r) * 7;
        float* rp = rois + ((size_t)b * 512 + rank) * 7;
        rp[0] = tb[0]; rp[1] = tb[1]; rp[2] = tb[2]; rp[3] = tb[3];
        rp[4] = tb[4]; rp[5] = tb[5]; rp[6] = tb[6];
        rsc[b * 512 + rank] = tsc[b * 1024 + r];
      }
      rank++;
    }
  }
  for (int z = total + lane; z < 512; z += 64) {
    float* rp = rois + ((size_t)b * 512 + z) * 7;
    rp[0] = rp[1] = rp[2] = rp[3] = rp[4] = rp[5] = rp[6] = 0.0f;
    rsc[b * 512 + z] = 0.0f;
  }
}

// ---------------- one 256x256 layer (4 rows per thread-half) + BN + ReLU ----------------
__device__ __forceinline__ void layer4(const float (*IN)[256], const float* __restrict__ W,
    const float* __restrict__ g, const float* __restrict__ bb, float (*OUT)[256], int t, int h)
{
  float acc[4] = {0, 0, 0, 0};
  const float* Wrow = W + (size_t)t * 256;
  for (int k = 0; k < 256; k += 4) {
    float4 w4 = *(const float4*)&Wrow[k];
#pragma unroll
    for (int r = 0; r < 4; ++r) {
      float4 xv = *(const float4*)&IN[h * 4 + r][k];
      acc[r] = fmaf(xv.x, w4.x, acc[r]);
      acc[r] = fmaf(xv.y, w4.y, acc[r]);
      acc[r] = fmaf(xv.z, w4.z, acc[r]);
      acc[r] = fmaf(xv.w, w4.w, acc[r]);
    }
  }
  float sc = g[t] / sqrtf(1.0f + 1e-5f);
  float bv = bb[t];
#pragma unroll
  for (int r = 0; r < 4; ++r)
    OUT[h * 4 + r][t] = fmaxf(fmaf(acc[r], sc, bv), 0.0f);
}

// ---------------- fused head chain (512 threads) ----------------
__global__ __launch_bounds__(512) void k_chain(const float* __restrict__ part,
    const float* __restrict__ Ws2, const float* __restrict__ Wc1, const float* __restrict__ Wc2,
    const float* __restrict__ Wr1, const float* __restrict__ Wr2,
    const float* __restrict__ g1, const float* __restrict__ b1,
    const float* __restrict__ g2, const float* __restrict__ b2,
    const float* __restrict__ gc1, const float* __restrict__ bc1,
    const float* __restrict__ gc2, const float* __restrict__ bc2,
    const float* __restrict__ gr1, const float* __restrict__ br1,
    const float* __restrict__ gr2, const float* __restrict__ br2,
    const float* __restrict__ Wc3, const float* __restrict__ bc3,
    const float* __restrict__ Wr3, const float* __restrict__ br3,
    const float* __restrict__ rois, const float* __restrict__ rsc,
    float* __restrict__ out)
{
  int bid = blockIdx.x, tid = threadIdx.x;
  int t = tid & 255, h = tid >> 8;
  __shared__ __align__(16) float bufX[8][256];
  __shared__ __align__(16) float bufY[8][256];
  __shared__ __align__(16) float bufC[8][256];
  __shared__ __align__(16) float bufR[8][256];
  __shared__ float hd[64];
  {
    float sc = g1[t] / sqrtf(1.0f + 1e-5f);
    float bv = b1[t];
#pragma unroll
    for (int r = 0; r < 4; ++r) {
      int row = h * 4 + r;
      float s = 0.f;
#pragma unroll
      for (int ks = 0; ks < KSPLIT; ++ks)
        s += part[(size_t)ks * 524288 + (size_t)(bid * 8 + row) * 256 + t];
      bufX[row][t] = fmaxf(fmaf(s, sc, bv), 0.0f);
    }
  }
  __syncthreads();
  layer4(bufX, Ws2, g2, b2, bufY, t, h);
  __syncthreads();
  layer4(bufY, Wc1, gc1, bc1, bufC, t, h);
  layer4(bufY, Wr1, gr1, br1, bufR, t, h);
  __syncthreads();
  layer4(bufC, Wc2, gc2, bc2, bufX, t, h);
  layer4(bufR, Wr2, gr2, br2, bufY, t, h);
  __syncthreads();
  int wv = tid >> 6, ln = tid & 63;
  for (int task = wv; task < 64; task += 8) {
    float p;
    if (task < 8) {
      float4 yv = *(const float4*)&bufX[task][ln * 4];
      float4 w4 = ((const float4*)Wc3)[ln];
      p = yv.x * w4.x + yv.y * w4.y + yv.z * w4.z + yv.w * w4.w;
    } else {
      int i = task - 8, row = i / 7, j = i % 7;
      float4 yv = *(const float4*)&bufY[row][ln * 4];
      float4 w4 = ((const float4*)(Wr3 + j * 256))[ln];
      p = yv.x * w4.x + yv.y * w4.y + yv.z * w4.z + yv.w * w4.w;
    }
#pragma unroll
    for (int off = 32; off > 0; off >>= 1) p += __shfl_xor(p, off, 64);
    if (ln == 0) hd[task] = p;
  }
  __syncthreads();
  if (tid < 8) {
    int m = bid * 8 + tid;
    float clsv = hd[tid] + bc3[0];
    float rg[7];
#pragma unroll
    for (int j = 0; j < 7; ++j) rg[j] = hd[8 + tid * 7 + j] + br3[j];
    const float* R = rois + (size_t)m * 7;
    float rx = R[0], ry = R[1], rz = R[2], dxa = R[3], dya = R[4], dza = R[5], ra = R[6];
    float diag = sqrtf(dxa * dxa + dya * dya);
    float x = rg[0] * diag, y = rg[1] * diag, z = rg[2] * dza;
    float ex = expf(rg[3]) * dxa, ey = expf(rg[4]) * dya, ez = expf(rg[5]) * dza;
    float hr = rg[6] + ra;
    float cc = cosf(ra), sn = sinf(ra);
    float xr = x * cc - y * sn, yr = x * sn + y * cc;
    float* O = out + (size_t)m * 9;
    O[0] = clsv; O[1] = xr + rx; O[2] = yr + ry; O[3] = z + rz;
    O[4] = ex; O[5] = ey; O[6] = ez; O[7] = hr; O[8] = rsc[m];
  }
}

// ---------------- launch ----------------
extern "C" void kernel_launch(void* const* d_in, const int* in_sizes, int n_in,
                              void* d_out, int out_size, void* d_ws, size_t ws_size,
                              hipStream_t stream)
{
  const float* rpn_box = (const float*)d_in[0];
  const float* rpn_cls = (const float*)d_in[1];
  const float* pooled  = (const float*)d_in[2];
  const float* Ws1 = (const float*)d_in[3];
  const float* g1  = (const float*)d_in[4];
  const float* b1  = (const float*)d_in[5];
  const float* Ws2 = (const float*)d_in[6];
  const float* g2  = (const float*)d_in[7];
  const float* b2  = (const float*)d_in[8];
  const float* Wc1 = (const float*)d_in[9];
  const float* gc1 = (const float*)d_in[10];
  const float* bc1 = (const float*)d_in[11];
  const float* Wc2 = (const float*)d_in[12];
  const float* gc2 = (const float*)d_in[13];
  const float* bc2 = (const float*)d_in[14];
  const float* Wc3 = (const float*)d_in[15];
  const float* bc3 = (const float*)d_in[16];
  const float* Wr1 = (const float*)d_in[17];
  const float* gr1 = (const float*)d_in[18];
  const float* br1 = (const float*)d_in[19];
  const float* Wr2 = (const float*)d_in[20];
  const float* gr2 = (const float*)d_in[21];
  const float* br2 = (const float*)d_in[22];
  const float* Wr3 = (const float*)d_in[23];
  const float* br3 = (const float*)d_in[24];

  if (ws_size < WS_NEED) return;

  char* ws = (char*)d_ws;
  u32* keys = (u32*)(ws + OF_KEYS);
  float* tbox = (float*)(ws + OF_TBOX);
  float* tsc  = (float*)(ws + OF_TSC);
  float* bx1 = (float*)(ws + OF_BX1);
  float* bx2 = (float*)(ws + OF_BX2);
  float* by1 = (float*)(ws + OF_BY1);
  float* by2 = (float*)(ws + OF_BY2);
  float* bar = (float*)(ws + OF_BAR);
  u32* mask = (u32*)(ws + OF_MASK);
  float* roisb = (float*)(ws + OF_ROIS);
  float* rscb  = (float*)(ws + OF_RSC);
  u32* Bsw = (u32*)(ws + OF_BSW);
  float* part = (float*)(ws + OF_PART);

  k_fatA<<<1139, 1024, 0, stream>>>(rpn_cls, Ws1, keys, Bsw);
  k_big<<<196, 1024, 0, stream>>>(keys, rpn_box, pooled, Bsw, part,
                                  tbox, tsc, bx1, bx2, by1, by2, bar);
  k_mask<<<64, 1024, 0, stream>>>(bx1, bx2, by1, by2, bar, mask);
  k_nms<<<4, 64, 0, stream>>>(mask, tbox, tsc, roisb, rscb);
  k_chain<<<256, 512, 0, stream>>>(part, Ws2, Wc1, Wc2, Wr1, Wr2,
                                   g1, b1, g2, b2, gc1, bc1, gc2, bc2,
                                   gr1, br1, gr2, br2, Wc3, bc3, Wr3, br3,
                                   roisb, rscb, (float*)d_out);
}